// Round 13
// baseline (244.218 us; speedup 1.0000x reference)
//
#include <hip/hip_runtime.h>

// ---------------------------------------------------------------------------
// CapsuleSequenceToGraph, fp32 in/out. B=64, T={128,512,256,256}, n=32, d=16.
// Identity: b_k[b,t,n] = <Vcum_k[b,n,:], pri[b,t,n,:]>, Vcum_k = sum_{i<k} v_i.
//
// pri ws layout (bf16), per mod: [b][t][n*16+d]  (B-MAJOR: route block (mod,b)
// owns a contiguous T KB region).
//
// Two kernels:
//   1) pri_kernel: pri = x @ W (bf16 MFMA). Block = (t-PAIR, 16-n half),
//      software-pipelined: W(t1) loads held in VGPRs across t0 compute
//      (launch_bounds(256,3) -> VGPR cap ~168; LDS caps at 3 blocks/CU).
//      UNCHANGED (not the critical dispatch).
//   2) route_kernel: ONE block per (mod,b) pair (256 blocks, 1024 thr).
//      Rounds 4/7/11 proved schedule variants are invariant (56.5-57.7us):
//      bottleneck is per-wave MLP — one iteration's 2KB in flight, ~1300cyc
//      exposed latency/iter (35 GB/s/CU). NOW: 2 rows per group per iter
//      (rows it*64+g, it*64+g+32) + depth-1 PAIR prefetch = 4KB/wave in
//      flight, 2x compute (~1760 elapsed cyc) between issue and wait.
//      (Round-11 OccupancyPercent 23.6% also exposed the audio/text load
//      imbalance — that is the NEXT lever, after this one is measured.)
// ---------------------------------------------------------------------------

typedef __attribute__((ext_vector_type(8))) short short8;
typedef __attribute__((ext_vector_type(4))) float floatx4;

static __device__ __forceinline__ unsigned short f2bf(float f) {
  union { float f; unsigned int i; } v;
  v.f = f;
  unsigned int x = v.i;
  return (unsigned short)((x + 0x7fffu + ((x >> 16) & 1u)) >> 16);  // RNE
}

// ---------------------------------------------------------------------------
// pri = x @ W, bf16 MFMA 16x16x32. Block = (t-pair, half): per t, M=64(b) x
// N=256(nd) x K=64(j). 1152 blocks. LDS 53KB -> 3 blocks/CU.
// ---------------------------------------------------------------------------
__global__ __launch_bounds__(256, 3) void pri_kernel(
    const float* __restrict__ x0, const float* __restrict__ x1,
    const float* __restrict__ x2, const float* __restrict__ x3,
    const float* __restrict__ w0, const float* __restrict__ w1,
    const float* __restrict__ w2, const float* __restrict__ w3,
    unsigned short* __restrict__ priAll) {
  __shared__ unsigned short wb[256 * 72];   // [nd_local][j] bf16, pitch 72
  __shared__ unsigned short sc[4][16][136]; // per-wave store-transpose scratch

  int blk = blockIdx.x;
  int tid = threadIdx.x;

  int pair = blk >> 1, half = blk & 1;
  const float* x;
  const float* W;
  unsigned short* priM;
  int T, t0;
  if (pair < 64)       { x = x0; W = w0; priM = priAll;               T = 128; t0 = 2 * pair; }
  else if (pair < 320) { x = x1; W = w1; priM = priAll + 4194304ull;  T = 512; t0 = 2 * (pair - 64); }
  else if (pair < 448) { x = x2; W = w2; priM = priAll + 20971520ull; T = 256; t0 = 2 * (pair - 320); }
  else                 { x = x3; W = w3; priM = priAll + 29360128ull; T = 256; t0 = 2 * (pair - 448); }
  size_t TS = (size_t)T * 512;  // b-row stride in shorts ([b][t][nd] layout)

  int lane = tid & 63, mt = tid >> 6;
  int m = lane & 15, q = lane >> 4;

  // ---- issue x loads for BOTH t (8 x floatx4, in flight together) ----
  floatx4 xv[8];
  {
    const float* xrow = x + ((size_t)(mt * 16 + m) * T + t0) * 64;
#pragma unroll
    for (int tt = 0; tt < 2; ++tt)
#pragma unroll
      for (int s = 0; s < 2; ++s) {
        const floatx4* xp = (const floatx4*)(xrow + tt * 64 + s * 32 + q * 8);
        xv[tt * 4 + s * 2]     = __builtin_nontemporal_load(xp);
        xv[tt * 4 + s * 2 + 1] = __builtin_nontemporal_load(xp + 1);
      }
  }

  // ---- issue W(t0) loads: 16 floatx4 explicitly in flight ----
  floatx4 wra[8], wrb[8];
  {
    const floatx4* Wf = (const floatx4*)(W + (size_t)t0 * 32768);
#pragma unroll
    for (int it = 0; it < 8; ++it) {
      int idx = it * 256 + tid;              // 0..2047
      int nl = idx >> 7, jp = (idx >> 2) & 31, dq = idx & 3;
      int ng = half * 16 + nl;
      wra[it] = __builtin_nontemporal_load(Wf + ng * 256 + (2 * jp) * 4 + dq);
      wrb[it] = __builtin_nontemporal_load(Wf + ng * 256 + (2 * jp + 1) * 4 + dq);
    }
  }

  // ---- build A fragments for both t while W loads fly ----
  short8 afrag[2][2];  // [tt][s]
#pragma unroll
  for (int tt = 0; tt < 2; ++tt)
#pragma unroll
    for (int s = 0; s < 2; ++s) {
      floatx4 u0 = xv[tt * 4 + s * 2], u1 = xv[tt * 4 + s * 2 + 1];
      short8 a;
      a[0] = (short)f2bf(u0[0]); a[1] = (short)f2bf(u0[1]);
      a[2] = (short)f2bf(u0[2]); a[3] = (short)f2bf(u0[3]);
      a[4] = (short)f2bf(u1[0]); a[5] = (short)f2bf(u1[1]);
      a[6] = (short)f2bf(u1[2]); a[7] = (short)f2bf(u1[3]);
      afrag[tt][s] = a;
    }

  unsigned int* wb32 = (unsigned int*)wb;  // pitch 36 dwords

  // ---- convert + write wb(t0) ----
#pragma unroll
  for (int it = 0; it < 8; ++it) {
    int idx = it * 256 + tid;
    int nl = idx >> 7, jp = (idx >> 2) & 31, dq = idx & 3;
    int rbase = nl * 16 + dq * 4;
#pragma unroll
    for (int k = 0; k < 4; ++k) {
      unsigned int dw = (unsigned int)f2bf(wra[it][k]) | ((unsigned int)f2bf(wrb[it][k]) << 16);
      wb32[(rbase + k) * 36 + jp] = dw;
    }
  }
  __syncthreads();

  // ---- issue W(t1) loads NOW; they stay in VGPRs across t0 compute ----
  {
    const floatx4* Wf = (const floatx4*)(W + (size_t)(t0 + 1) * 32768);
#pragma unroll
    for (int it = 0; it < 8; ++it) {
      int idx = it * 256 + tid;
      int nl = idx >> 7, jp = (idx >> 2) & 31, dq = idx & 3;
      int ng = half * 16 + nl;
      wra[it] = __builtin_nontemporal_load(Wf + ng * 256 + (2 * jp) * 4 + dq);
      wrb[it] = __builtin_nontemporal_load(Wf + ng * 256 + (2 * jp + 1) * 4 + dq);
    }
  }

  // ---- compute one t: 16 N-tiles; D: row b = mt*16+q*4+reg, col nd = nt*16+m
  // store to [b][t][nd]: addr = b*TS + t*512 + nd
  auto compute_t = [&](const short8& a0, const short8& a1, int t) {
    unsigned short* dst = priM + (size_t)t * 512 + half * 256;
    for (int g2 = 0; g2 < 2; ++g2) {
#pragma unroll
      for (int k = 0; k < 8; ++k) {
        int nt = g2 * 8 + k;
        const short8* b0p = (const short8*)&wb[(nt * 16 + m) * 72 + q * 8];
        const short8* b1p = (const short8*)&wb[(nt * 16 + m) * 72 + 32 + q * 8];
        short8 bf0 = *b0p, bf1 = *b1p;
        floatx4 acc = {0.f, 0.f, 0.f, 0.f};
        acc = __builtin_amdgcn_mfma_f32_16x16x32_bf16(a0, bf0, acc, 0, 0, 0);
        acc = __builtin_amdgcn_mfma_f32_16x16x32_bf16(a1, bf1, acc, 0, 0, 0);
#pragma unroll
        for (int reg = 0; reg < 4; ++reg)
          sc[mt][q * 4 + reg][k * 16 + m] = f2bf(acc[reg]);
      }
#pragma unroll
      for (int i = 0; i < 4; ++i) {
        int bl = (lane >> 4) + i * 4;
        int sh = (lane & 15) * 8;
        short8 v = *(const short8*)&sc[mt][bl][sh];
        *(short8*)(dst + (size_t)(mt * 16 + bl) * TS + g2 * 128 + sh) = v;
      }
    }
  };

  compute_t(afrag[0][0], afrag[0][1], t0);
  __syncthreads();  // all waves done reading wb(t0)

  // ---- convert + write wb(t1) ----
#pragma unroll
  for (int it = 0; it < 8; ++it) {
    int idx = it * 256 + tid;
    int nl = idx >> 7, jp = (idx >> 2) & 31, dq = idx & 3;
    int rbase = nl * 16 + dq * 4;
#pragma unroll
    for (int k = 0; k < 4; ++k) {
      unsigned int dw = (unsigned int)f2bf(wra[it][k]) | ((unsigned int)f2bf(wrb[it][k]) << 16);
      wb32[(rbase + k) * 36 + jp] = dw;
    }
  }
  __syncthreads();

  compute_t(afrag[1][0], afrag[1][1], t0 + 1);
}

// ---------------------------------------------------------------------------
// route_kernel: block = one (mod, b) pair. 1024 threads = 32 groups of 32.
// Group g handles 2 rows per iteration: t = it*64+g and it*64+g+32, with a
// depth-1 PAIR prefetch (4 loads = 4KB/wave in flight; 2 row-computes
// between issue and the bottom-of-loop wait). asm keep-alive pins the
// prefetch issue at the top. launch_bounds(1024,4) -> 128 VGPR cap.
// All 4 routing passes in-block; Vcum in LDS (pitch-17). Softmax without
// max-subtraction (|logit| bounded << fp32 exp range).
// LDS ~84KB -> exactly 1 block/CU (256 blocks on 256 CUs).
// ---------------------------------------------------------------------------
__global__ __launch_bounds__(1024, 4) void route_kernel(
    const unsigned short* __restrict__ priAll, float* __restrict__ out) {
  __shared__ float Sl[32][640];   // [group][n*17+d], pitch 640 (occupancy pin)
  __shared__ float Vc_s[544];     // Vcum, [n*17+d]

  int blk = blockIdx.x;
  int mod = blk & 3, b = blk >> 2;
  size_t poff; int T;
  if (mod == 0)      { poff = 0ull;         T = 128; }
  else if (mod == 1) { poff = 4194304ull;   T = 512; }
  else if (mod == 2) { poff = 20971520ull;  T = 256; }
  else               { poff = 29360128ull;  T = 256; }

  // [b][t][nd]: this block's slice is contiguous T KB
  const unsigned short* priM = priAll + poff + (size_t)b * T * 512;

  int tid = threadIdx.x;
  int n = tid & 31, g = tid >> 5;
  int nbase = n * 17;

  if (tid < 544) Vc_s[tid] = 0.f;
  __syncthreads();

  int iters2 = T >> 6;  // row-PAIRS per group per pass (>= 2)

  for (int pass = 0; pass < 4; ++pass) {
    float Vc[16];
#pragma unroll
    for (int d = 0; d < 16; ++d) Vc[d] = Vc_s[nbase + d];

    float acc[16];
#pragma unroll
    for (int d = 0; d < 16; ++d) acc[d] = 0.f;

    // rows t = it*64+g and it*64+g+32; row = 64 uint4, pair stride = 4096
    const uint4* pr = (const uint4*)(priM + (size_t)g * 512 + n * 16);
    uint4 c0a = pr[0], c0b = pr[1];           // row g
    uint4 c1a = pr[2048], c1b = pr[2049];     // row g+32

    for (int it = 0; it < iters2; ++it) {
      // depth-1 pair prefetch, unconditional via clamped offset
      int po = (it + 1 < iters2) ? 4096 : 0;
      uint4 f0a = pr[po], f0b = pr[po + 1];
      uint4 f1a = pr[po + 2048], f1b = pr[po + 2049];

#pragma unroll
      for (int rr = 0; rr < 2; ++rr) {
        uint4 ca = rr ? c1a : c0a;
        uint4 cb = rr ? c1b : c0b;
        float p[16];
        {
          unsigned int wds[8] = {ca.x, ca.y, ca.z, ca.w, cb.x, cb.y, cb.z, cb.w};
#pragma unroll
          for (int k = 0; k < 8; ++k) {
            union { unsigned int u; float f; } lo, hi;
            lo.u = wds[k] << 16;
            hi.u = wds[k] & 0xffff0000u;
            p[2 * k] = lo.f;
            p[2 * k + 1] = hi.f;
          }
        }
        float logit = 0.f;
#pragma unroll
        for (int d = 0; d < 16; ++d) logit += p[d] * Vc[d];
        float e = __expf(logit);
        float s = e;
#pragma unroll
        for (int o = 16; o >= 1; o >>= 1) s += __shfl_xor(s, o, 32);
        float rc = e / s;
#pragma unroll
        for (int d = 0; d < 16; ++d) acc[d] += rc * p[d];
      }

      // fixed consumption point after BOTH row-computes: loads issued at the
      // top stay there; wait lands here (~1760 elapsed cyc of cover).
      asm volatile("" :: "v"(f0a.x), "v"(f0a.w), "v"(f0b.x), "v"(f0b.w),
                         "v"(f1a.x), "v"(f1a.w), "v"(f1b.x), "v"(f1b.w));

      c0a = f0a; c0b = f0b; c1a = f1a; c1b = f1b;
      pr += 4096;
    }

#pragma unroll
    for (int d = 0; d < 16; ++d) Sl[g][nbase + d] = acc[d];
    __syncthreads();

    if (tid < 512) {
      int nn = tid >> 4, dd = tid & 15;
      int idx = nn * 17 + dd;
      float s = 0.f;
#pragma unroll
      for (int gg = 0; gg < 32; ++gg) s += Sl[gg][idx];
      float v = tanhf(s);
      if (pass == 3) out[(size_t)(mod * 64 + b) * 512 + tid] = v;
      else Vc_s[idx] += v;
    }
    __syncthreads();
  }
}

extern "C" void kernel_launch(void* const* d_in, const int* in_sizes, int n_in,
                              void* d_out, int out_size, void* d_ws, size_t ws_size,
                              hipStream_t stream) {
  const float* x0 = (const float*)d_in[0];
  const float* x1 = (const float*)d_in[1];
  const float* x2 = (const float*)d_in[2];
  const float* x3 = (const float*)d_in[3];
  const float* w0 = (const float*)d_in[4];
  const float* w1 = (const float*)d_in[5];
  const float* w2 = (const float*)d_in[6];
  const float* w3 = (const float*)d_in[7];

  unsigned short* pri = (unsigned short*)d_ws;

  pri_kernel<<<1152, 256, 0, stream>>>(x0, x1, x2, x3, w0, w1, w2, w3, pri);
  route_kernel<<<256, 1024, 0, stream>>>(pri, (float*)d_out);
}